// Round 1
// baseline (245.102 us; speedup 1.0000x reference)
//
#include <hip/hip_runtime.h>
#include <hip/hip_bf16.h>
#include <math.h>

#define N_PROT 50000
#define N_SUB  2000
#define D_PROT 256
#define D_SUB  256
#define D_PROJ 128
#define KW     16
#define N_INT  64
#define NWIN   (N_PROT - KW + 1)

// output layout (floats)
#define OUT_SUB (N_PROT * D_PROT)                 // 12,800,000
#define OUT_IDX (OUT_SUB + N_SUB * D_SUB)         // 13,312,000

// ws layout (floats)
// [0..1]   packed argmax (unsigned long long)
// [2..129] reaction[128]
// [132..]  g[N_PROT]
// [132+N_PROT..] P[N_PROT]
#define WS_REACT 2
#define WS_G     132
#define WS_P     (WS_G + N_PROT)

// ---------------- K1: reaction = sum(sub[idx] @ Ws + bs) ; init argmax slot ---
__global__ __launch_bounds__(256) void k_reaction(
    const float* __restrict__ sub_node, const int* __restrict__ int_index,
    const float* __restrict__ Ws, const float* __restrict__ bs,
    float* __restrict__ ws) {
  __shared__ int   sidx[N_INT];
  __shared__ float ssum[D_SUB];
  int tid = threadIdx.x;
  if (tid < N_INT) sidx[tid] = int_index[tid];
  __syncthreads();
  float acc = 0.f;
  #pragma unroll 8
  for (int i = 0; i < N_INT; ++i) acc += sub_node[sidx[i] * D_SUB + tid];
  ssum[tid] = acc;
  __syncthreads();
  if (tid < D_PROJ) {
    float r = 64.0f * bs[tid];
    #pragma unroll 8
    for (int d = 0; d < D_SUB; ++d) r = fmaf(ssum[d], Ws[d * D_PROJ + tid], r);
    ws[WS_REACT + tid] = r;
  }
  if (tid == 0) *((unsigned long long*)ws) = 0ull;   // argmax packed init
}

// ---------------- K2: proj GEMM (not stored); emits g, P, and copies prot->out
#define MB 32
#define KC 32
#define AS_STRIDE 36   // 32 + 4 pad (conflict-free b128 writes)

__global__ __launch_bounds__(256) void k_gemm(
    const float* __restrict__ prot, const float* __restrict__ Wp,
    const float* __restrict__ bp, const float* __restrict__ wa,
    float* __restrict__ out, float* __restrict__ ws) {
  __shared__ float Bs[KC * D_PROJ];       // 16 KB
  __shared__ float As[MB * AS_STRIDE];    // 4.6 KB
  __shared__ float redG[4][16], redP[4][16];
  const int tid = threadIdx.x;
  const int j = tid & 127, mh = tid >> 7;
  const int row0 = blockIdx.x * MB;
  const int r = tid >> 3, q = tid & 7;    // A-tile load mapping
  float acc[16];
  #pragma unroll
  for (int m = 0; m < 16; ++m) acc[m] = 0.f;

  for (int kc = 0; kc < D_PROT / KC; ++kc) {
    // stage Wp chunk (KC x 128, contiguous)
    const float* wpc = Wp + kc * KC * D_PROJ;
    #pragma unroll
    for (int u = 0; u < 4; ++u) {
      int idx = u * 1024 + tid * 4;
      *(float4*)&Bs[idx] = *(const float4*)&wpc[idx];
    }
    // stage A chunk (MB rows x KC) + fused prot->out copy
    int arow = row0 + r;
    int goff = arow * D_PROT + kc * KC + q * 4;
    float4 av = make_float4(0.f, 0.f, 0.f, 0.f);
    if (arow < N_PROT) {
      av = *(const float4*)&prot[goff];
      *(float4*)&out[goff] = av;
    }
    *(float4*)&As[r * AS_STRIDE + q * 4] = av;
    __syncthreads();
    #pragma unroll
    for (int k4 = 0; k4 < KC / 4; ++k4) {
      float b0 = Bs[(k4 * 4 + 0) * D_PROJ + j];
      float b1 = Bs[(k4 * 4 + 1) * D_PROJ + j];
      float b2 = Bs[(k4 * 4 + 2) * D_PROJ + j];
      float b3 = Bs[(k4 * 4 + 3) * D_PROJ + j];
      #pragma unroll
      for (int m = 0; m < 16; ++m) {
        float4 a = *(const float4*)&As[(mh * 16 + m) * AS_STRIDE + k4 * 4];
        acc[m] = fmaf(a.x, b0, fmaf(a.y, b1, fmaf(a.z, b2, fmaf(a.w, b3, acc[m]))));
      }
    }
    __syncthreads();
  }
  // epilogue: proj = acc + bp[j]; reduce over j for g (proj.w1) and P (row sum)
  const float bpj = bp[j];
  const float w1j = wa[j];           // w1 = wa[:128]
  const int lane = tid & 63, wid = tid >> 6;
  #pragma unroll
  for (int m = 0; m < 16; ++m) {
    float v = acc[m] + bpj;
    float pg = v * w1j;
    float pp = v;
    #pragma unroll
    for (int off = 32; off > 0; off >>= 1) {
      pg += __shfl_xor(pg, off, 64);
      pp += __shfl_xor(pp, off, 64);
    }
    if (lane == 0) { redG[wid][m] = pg; redP[wid][m] = pp; }
  }
  __syncthreads();
  if (tid < 32) {
    int mh2 = tid >> 4, m = tid & 15;
    int row = row0 + mh2 * 16 + m;
    if (row < N_PROT) {
      ws[WS_G + row] = redG[mh2 * 2][m] + redG[mh2 * 2 + 1][m];
      ws[WS_P + row] = redP[mh2 * 2][m] + redP[mh2 * 2 + 1][m];
    }
  }
}

// ---------------- K3: copy sub_node -> out, int_index -> out (as float) ------
__global__ __launch_bounds__(256) void k_copy_sub(
    const float* __restrict__ sub_node, const int* __restrict__ int_index,
    float* __restrict__ out) {
  int i = blockIdx.x * blockDim.x + threadIdx.x;   // 128000 float4's
  float4 v = *(const float4*)&sub_node[i * 4];
  *(float4*)&out[OUT_SUB + i * 4] = v;
  if (i < N_INT) out[OUT_IDX + i] = (float)int_index[i];
}

// ---------------- K4: per-window softmax score + global argmax (packed u64) --
__global__ __launch_bounds__(256) void k_window(
    const float* __restrict__ ws, unsigned long long* __restrict__ packed) {
  __shared__ float sg[256 + KW], sp[256 + KW];
  __shared__ unsigned long long wred[4];
  const int tid = threadIdx.x;
  const int w0 = blockIdx.x * 256;
  for (int i = tid; i < 256 + KW - 1; i += 256) {
    int idx = w0 + i;
    bool ok = idx < N_PROT;
    sg[i] = ok ? ws[WS_G + idx] : -1e30f;
    sp[i] = ok ? ws[WS_P + idx] : 0.f;
  }
  __syncthreads();
  int w = w0 + tid;
  unsigned long long best = 0ull;
  if (w < NWIN) {
    float m = sg[tid];
    #pragma unroll
    for (int k = 1; k < KW; ++k) m = fmaxf(m, sg[tid + k]);
    float s = 0.f, t = 0.f;
    #pragma unroll
    for (int k = 0; k < KW; ++k) {
      float e = expf(sg[tid + k] - m);
      s += e;
      t = fmaf(e, sp[tid + k], t);
    }
    t /= s;   // + R (const) dropped: argmax-invariant
    unsigned int b = __float_as_uint(t);
    unsigned int u = b ^ ((b & 0x80000000u) ? 0xFFFFFFFFu : 0x80000000u);
    // tie-break: smaller w wins (matches jnp.argmax first-occurrence)
    best = ((unsigned long long)u << 32) |
           (unsigned long long)(0xFFFFFFFFu - (unsigned)w);
  }
  #pragma unroll
  for (int off = 32; off > 0; off >>= 1) {
    unsigned long long o = __shfl_xor(best, off, 64);
    if (o > best) best = o;
  }
  if ((tid & 63) == 0) wred[tid >> 6] = best;
  __syncthreads();
  if (tid == 0) {
    unsigned long long b2 = wred[0];
    for (int i = 1; i < 4; ++i) if (wred[i] > b2) b2 = wred[i];
    atomicMax(packed, b2);
  }
}

// ---------------- K5: top_score, deltas, patch the 16 prot rows + 64 sub rows
__global__ __launch_bounds__(256) void k_final(
    const float* __restrict__ prot, const float* __restrict__ sub_node,
    const int* __restrict__ int_index, const float* __restrict__ Wp,
    const float* __restrict__ bp, const float* __restrict__ sub_out,
    const float* __restrict__ prot_out, const float* __restrict__ ws,
    float* __restrict__ out) {
  __shared__ float aprot[KW][D_PROT];    // 16 KB
  __shared__ float proj16[KW][D_PROJ];   // 8 KB
  __shared__ float attn[KW];
  __shared__ float ts[D_PROJ];
  __shared__ float pdelta[D_PROT], sdelta[D_SUB];
  const int tid = threadIdx.x;
  unsigned long long pk = *(const unsigned long long*)ws;
  const int wtop = (int)(0xFFFFFFFFu - (unsigned)(pk & 0xFFFFFFFFull));

  for (int i = tid; i < KW * D_PROT; i += 256) {
    int rr = i >> 8, dd = i & 255;
    aprot[rr][dd] = prot[(wtop + rr) * D_PROT + dd];
  }
  __syncthreads();
  // recompute proj for the 16 window rows
  const int j = tid & 127, half = tid >> 7;
  float accr[8];
  #pragma unroll
  for (int rr = 0; rr < 8; ++rr) accr[rr] = bp[j];
  for (int k = 0; k < D_PROT; ++k) {
    float wv = Wp[k * D_PROJ + j];
    #pragma unroll
    for (int rr = 0; rr < 8; ++rr)
      accr[rr] = fmaf(aprot[half * 8 + rr][k], wv, accr[rr]);
  }
  #pragma unroll
  for (int rr = 0; rr < 8; ++rr) proj16[half * 8 + rr][j] = accr[rr];
  __syncthreads();
  if (tid == 0) {   // softmax over g[wtop..wtop+15] (shift-invariant vs ref)
    float m = ws[WS_G + wtop];
    for (int k = 1; k < KW; ++k) m = fmaxf(m, ws[WS_G + wtop + k]);
    float e[KW], s = 0.f;
    for (int k = 0; k < KW; ++k) { e[k] = expf(ws[WS_G + wtop + k] - m); s += e[k]; }
    for (int k = 0; k < KW; ++k) attn[k] = e[k] / s;
  }
  __syncthreads();
  if (tid < D_PROJ) {
    float a = ws[WS_REACT + tid];
    #pragma unroll
    for (int k = 0; k < KW; ++k) a = fmaf(attn[k], proj16[k][tid], a);
    ts[tid] = a;
  }
  __syncthreads();
  {
    float pa = 0.f, sa = 0.f;
    #pragma unroll 8
    for (int jj = 0; jj < D_PROJ; ++jj) {
      float t = ts[jj];
      pa = fmaf(t, prot_out[jj * D_PROT + tid], pa);
      sa = fmaf(t, sub_out[jj * D_SUB + tid], sa);
    }
    pdelta[tid] = pa; sdelta[tid] = sa;
  }
  __syncthreads();
  for (int i = tid; i < KW * D_PROT; i += 256) {
    int rr = i >> 8, dd = i & 255;
    out[(wtop + rr) * D_PROT + dd] = aprot[rr][dd] + pdelta[dd];
  }
  for (int i = 0; i < N_INT; ++i) {   // duplicates: same value, set-safe
    int idx = int_index[i];
    out[OUT_SUB + idx * D_SUB + tid] = sub_node[idx * D_SUB + tid] + sdelta[tid];
  }
}

extern "C" void kernel_launch(void* const* d_in, const int* in_sizes, int n_in,
                              void* d_out, int out_size, void* d_ws, size_t ws_size,
                              hipStream_t stream) {
  const float* prot     = (const float*)d_in[0];
  const float* sub      = (const float*)d_in[1];
  const int*   idx      = (const int*)d_in[2];
  const float* Wp       = (const float*)d_in[3];
  const float* bp       = (const float*)d_in[4];
  const float* Ws       = (const float*)d_in[5];
  const float* bs       = (const float*)d_in[6];
  const float* wa       = (const float*)d_in[7];
  // d_in[8] = ba: unused — additive constant cancels in softmax
  const float* sub_out  = (const float*)d_in[9];
  const float* prot_out = (const float*)d_in[10];
  float* out = (float*)d_out;
  float* ws  = (float*)d_ws;

  k_reaction<<<1, 256, 0, stream>>>(sub, idx, Ws, bs, ws);
  k_gemm<<<(N_PROT + MB - 1) / MB, 256, 0, stream>>>(prot, Wp, bp, wa, out, ws);
  k_copy_sub<<<(N_SUB * D_SUB) / (256 * 4), 256, 0, stream>>>(sub, idx, out);
  k_window<<<(NWIN + 255) / 256, 256, 0, stream>>>(ws, (unsigned long long*)ws);
  k_final<<<1, 256, 0, stream>>>(prot, sub, idx, Wp, bp, sub_out, prot_out, ws, out);
}

// Round 2
// 183.445 us; speedup vs baseline: 1.3361x; 1.3361x over previous
//
#include <hip/hip_runtime.h>
#include <hip/hip_bf16.h>
#include <math.h>

#define N_PROT 50000
#define N_SUB  2000
#define D_PROT 256
#define D_SUB  256
#define D_PROJ 128
#define KW     16
#define N_INT  64
#define NWIN   (N_PROT - KW + 1)

// output layout (floats)
#define OUT_SUB (N_PROT * D_PROT)                 // 12,800,000
#define OUT_IDX (OUT_SUB + N_SUB * D_SUB)         // 13,312,000

// ws layout (floats)
#define WS_PACK  0                                // [0..1] packed argmax u64
#define WS_REACT 2                                // [2..129] reaction
#define WS_U1    132                              // [132..387] u1 = Wp @ w1
#define WS_U2    388                              // [388..643] u2 = Wp @ ones
#define WS_G     644                              // g[N_PROT]  (no constant term)
#define WS_P     (WS_G + N_PROT)                  // P[N_PROT]  (no constant term)

// ---------------- K1 (2 blocks): block0 = reaction + argmax init; block1 = u1,u2
__global__ __launch_bounds__(256) void k_prep(
    const float* __restrict__ sub_node, const int* __restrict__ int_index,
    const float* __restrict__ Ws, const float* __restrict__ bs,
    const float* __restrict__ Wp, const float* __restrict__ wa,
    float* __restrict__ ws) {
  const int tid = threadIdx.x;
  if (blockIdx.x == 0) {
    __shared__ int   sidx[N_INT];
    __shared__ float ssum[D_SUB];
    if (tid < N_INT) sidx[tid] = int_index[tid];
    __syncthreads();
    float acc = 0.f;
    #pragma unroll 8
    for (int i = 0; i < N_INT; ++i) acc += sub_node[sidx[i] * D_SUB + tid];
    ssum[tid] = acc;
    __syncthreads();
    if (tid < D_PROJ) {
      float r = 64.0f * bs[tid];
      #pragma unroll 8
      for (int d = 0; d < D_SUB; ++d) r = fmaf(ssum[d], Ws[d * D_PROJ + tid], r);
      ws[WS_REACT + tid] = r;
    }
    if (tid == 0) *((unsigned long long*)ws) = 0ull;
  } else {
    // u1[k] = sum_j Wp[k][j] * wa[j];  u2[k] = sum_j Wp[k][j]
    __shared__ float swa[D_PROJ];
    if (tid < D_PROJ) swa[tid] = wa[tid];
    __syncthreads();
    float s1 = 0.f, s2 = 0.f;
    const float4* wrow = (const float4*)&Wp[tid * D_PROJ];
    #pragma unroll 8
    for (int j4 = 0; j4 < D_PROJ / 4; ++j4) {
      float4 w = wrow[j4];
      float4 a = *(const float4*)&swa[j4 * 4];
      s1 = fmaf(w.x, a.x, fmaf(w.y, a.y, fmaf(w.z, a.z, fmaf(w.w, a.w, s1))));
      s2 += w.x + w.y + w.z + w.w;
    }
    ws[WS_U1 + tid] = s1;
    ws[WS_U2 + tid] = s2;
  }
}

// ---------------- K2: streaming — copy prot->out, emit g=A@u1, P=A@u2;
//                  spare blocks copy sub->out and int_index->out.
#define PB 782   // 782*64 = 50048 rows covered
#define SB 8     // 8 blocks copy 2000*256 floats (16000 float4 each)

__global__ __launch_bounds__(256) void k_rows(
    const float* __restrict__ prot, const float* __restrict__ sub_node,
    const int* __restrict__ int_index, float* __restrict__ out,
    float* __restrict__ ws) {
  const int tid = threadIdx.x, lane = tid & 63, wave = tid >> 6;
  if (blockIdx.x < PB) {
    const float4 c1 = *(const float4*)&ws[WS_U1 + lane * 4];
    const float4 c2 = *(const float4*)&ws[WS_U2 + lane * 4];
    const int rbase = blockIdx.x * 64 + wave * 16;
    if (rbase + 16 <= N_PROT) {
      #pragma unroll 4
      for (int i = 0; i < 16; ++i) {
        const int r = rbase + i;
        const float4 av = *(const float4*)&prot[r * D_PROT + lane * 4];
        *(float4*)&out[r * D_PROT + lane * 4] = av;
        float g = av.x * c1.x + av.y * c1.y + av.z * c1.z + av.w * c1.w;
        float p = av.x * c2.x + av.y * c2.y + av.z * c2.z + av.w * c2.w;
        #pragma unroll
        for (int off = 32; off > 0; off >>= 1) {
          g += __shfl_xor(g, off, 64);
          p += __shfl_xor(p, off, 64);
        }
        if (lane == 0) { ws[WS_G + r] = g; ws[WS_P + r] = p; }
      }
    } else {
      for (int i = 0; i < 16; ++i) {
        const int r = rbase + i;
        if (r >= N_PROT) break;
        const float4 av = *(const float4*)&prot[r * D_PROT + lane * 4];
        *(float4*)&out[r * D_PROT + lane * 4] = av;
        float g = av.x * c1.x + av.y * c1.y + av.z * c1.z + av.w * c1.w;
        float p = av.x * c2.x + av.y * c2.y + av.z * c2.z + av.w * c2.w;
        for (int off = 32; off > 0; off >>= 1) {
          g += __shfl_xor(g, off, 64);
          p += __shfl_xor(p, off, 64);
        }
        if (lane == 0) { ws[WS_G + r] = g; ws[WS_P + r] = p; }
      }
    }
  } else {
    const int sb = blockIdx.x - PB;
    #pragma unroll 4
    for (int i = tid; i < 16000; i += 256) {
      const int gi = sb * 16000 + i;
      *(float4*)&out[OUT_SUB + gi * 4] = *(const float4*)&sub_node[gi * 4];
    }
    if (sb == 0 && tid < N_INT) out[OUT_IDX + tid] = (float)int_index[tid];
  }
}

// ---------------- K3: per-window softmax score + global argmax (packed u64) --
__global__ __launch_bounds__(256) void k_window(
    const float* __restrict__ ws, unsigned long long* __restrict__ packed) {
  __shared__ float sg[256 + KW], sp[256 + KW];
  __shared__ unsigned long long wred[4];
  const int tid = threadIdx.x;
  const int w0 = blockIdx.x * 256;
  for (int i = tid; i < 256 + KW - 1; i += 256) {
    int idx = w0 + i;
    bool ok = idx < N_PROT;
    sg[i] = ok ? ws[WS_G + idx] : -1e30f;
    sp[i] = ok ? ws[WS_P + idx] : 0.f;
  }
  __syncthreads();
  int w = w0 + tid;
  unsigned long long best = 0ull;
  if (w < NWIN) {
    float m = sg[tid];
    #pragma unroll
    for (int k = 1; k < KW; ++k) m = fmaxf(m, sg[tid + k]);
    float s = 0.f, t = 0.f;
    #pragma unroll
    for (int k = 0; k < KW; ++k) {
      float e = expf(sg[tid + k] - m);
      s += e;
      t = fmaf(e, sp[tid + k], t);
    }
    t /= s;   // + const dropped: argmax-invariant
    unsigned int b = __float_as_uint(t);
    unsigned int u = b ^ ((b & 0x80000000u) ? 0xFFFFFFFFu : 0x80000000u);
    best = ((unsigned long long)u << 32) |
           (unsigned long long)(0xFFFFFFFFu - (unsigned)w);
  }
  #pragma unroll
  for (int off = 32; off > 0; off >>= 1) {
    unsigned long long o = __shfl_xor(best, off, 64);
    if (o > best) best = o;
  }
  if ((tid & 63) == 0) wred[tid >> 6] = best;
  __syncthreads();
  if (tid == 0) {
    unsigned long long b2 = wred[0];
    for (int i = 1; i < 4; ++i) if (wred[i] > b2) b2 = wred[i];
    atomicMax(packed, b2);
  }
}

// ---------------- K4: top_score, deltas, patch 16 prot rows + 64 sub rows ----
__global__ __launch_bounds__(256) void k_final(
    const float* __restrict__ prot, const float* __restrict__ sub_node,
    const int* __restrict__ int_index, const float* __restrict__ Wp,
    const float* __restrict__ bp, const float* __restrict__ sub_out,
    const float* __restrict__ prot_out, const float* __restrict__ ws,
    float* __restrict__ out) {
  __shared__ float aprot[KW][D_PROT];    // 16 KB
  __shared__ float proj16[KW][D_PROJ];   // 8 KB
  __shared__ float attn[KW];
  __shared__ float ts[D_PROJ];
  __shared__ float pdelta[D_PROT], sdelta[D_SUB];
  __shared__ int   sidx[N_INT];
  const int tid = threadIdx.x;
  unsigned long long pk = *(const unsigned long long*)ws;
  const int wtop = (int)(0xFFFFFFFFu - (unsigned)(pk & 0xFFFFFFFFull));

  if (tid < N_INT) sidx[tid] = int_index[tid];
  for (int i = tid; i < KW * D_PROT; i += 256) {
    int rr = i >> 8, dd = i & 255;
    aprot[rr][dd] = prot[(wtop + rr) * D_PROT + dd];
  }
  __syncthreads();
  // recompute proj (f32, same math as reference) for the 16 window rows
  const int j = tid & 127, half = tid >> 7;
  float accr[8];
  #pragma unroll
  for (int rr = 0; rr < 8; ++rr) accr[rr] = bp[j];
  for (int k = 0; k < D_PROT; ++k) {
    float wv = Wp[k * D_PROJ + j];
    #pragma unroll
    for (int rr = 0; rr < 8; ++rr)
      accr[rr] = fmaf(aprot[half * 8 + rr][k], wv, accr[rr]);
  }
  #pragma unroll
  for (int rr = 0; rr < 8; ++rr) proj16[half * 8 + rr][j] = accr[rr];
  __syncthreads();
  if (tid == 0) {   // softmax over g window (shift-invariant vs ref)
    float m = ws[WS_G + wtop];
    for (int k = 1; k < KW; ++k) m = fmaxf(m, ws[WS_G + wtop + k]);
    float e[KW], s = 0.f;
    for (int k = 0; k < KW; ++k) { e[k] = expf(ws[WS_G + wtop + k] - m); s += e[k]; }
    for (int k = 0; k < KW; ++k) attn[k] = e[k] / s;
  }
  __syncthreads();
  if (tid < D_PROJ) {
    float a = ws[WS_REACT + tid];
    #pragma unroll
    for (int k = 0; k < KW; ++k) a = fmaf(attn[k], proj16[k][tid], a);
    ts[tid] = a;
  }
  __syncthreads();
  {
    float pa = 0.f, sa = 0.f;
    #pragma unroll 8
    for (int jj = 0; jj < D_PROJ; ++jj) {
      float t = ts[jj];
      pa = fmaf(t, prot_out[jj * D_PROT + tid], pa);
      sa = fmaf(t, sub_out[jj * D_SUB + tid], sa);
    }
    pdelta[tid] = pa; sdelta[tid] = sa;
  }
  __syncthreads();
  for (int i = tid; i < KW * D_PROT; i += 256) {
    int rr = i >> 8, dd = i & 255;
    out[(wtop + rr) * D_PROT + dd] = aprot[rr][dd] + pdelta[dd];
  }
  for (int i = 0; i < N_INT; ++i) {   // duplicates: same value, set-safe
    int idx = sidx[i];
    out[OUT_SUB + idx * D_SUB + tid] = sub_node[idx * D_SUB + tid] + sdelta[tid];
  }
}

extern "C" void kernel_launch(void* const* d_in, const int* in_sizes, int n_in,
                              void* d_out, int out_size, void* d_ws, size_t ws_size,
                              hipStream_t stream) {
  const float* prot     = (const float*)d_in[0];
  const float* sub      = (const float*)d_in[1];
  const int*   idx      = (const int*)d_in[2];
  const float* Wp       = (const float*)d_in[3];
  const float* bp       = (const float*)d_in[4];
  const float* Ws       = (const float*)d_in[5];
  const float* bs       = (const float*)d_in[6];
  const float* wa       = (const float*)d_in[7];
  // d_in[8] = ba unused (cancels in softmax); wa[128:] unused (constant in g)
  const float* sub_out  = (const float*)d_in[9];
  const float* prot_out = (const float*)d_in[10];
  float* out = (float*)d_out;
  float* ws  = (float*)d_ws;

  k_prep<<<2, 256, 0, stream>>>(sub, idx, Ws, bs, Wp, wa, ws);
  k_rows<<<PB + SB, 256, 0, stream>>>(prot, sub, idx, out, ws);
  k_window<<<(NWIN + 255) / 256, 256, 0, stream>>>(ws, (unsigned long long*)ws);
  k_final<<<1, 256, 0, stream>>>(prot, sub, idx, Wp, bp, sub_out, prot_out, ws, out);
}